// Round 4
// baseline (963.558 us; speedup 1.0000x reference)
//
#include <hip/hip_runtime.h>
#include <hip/hip_bf16.h>

#define N_PTS 8192
#define KNN 8
#define GRID_DIM 32
#define NCELLS 32768           // 32^3
#define CELL_S 0.25f
#define GRID_LO (-4.0f)

typedef __attribute__((ext_vector_type(8))) short short8;
typedef __attribute__((ext_vector_type(4))) float float4v;
typedef unsigned long long u64;
typedef unsigned int u32;

// f32 -> bf16 round-to-nearest-even (finite inputs only)
static __device__ __forceinline__ short f2bf(float f) {
    unsigned u = __float_as_uint(f);
    unsigned r = (u + 0x7FFFu + ((u >> 16) & 1u)) >> 16;
    return (short)r;
}
static __device__ __forceinline__ float bf2f(short s) {
    return __uint_as_float(((unsigned)(unsigned short)s) << 16);
}

static __device__ __forceinline__ void ins8(u64* best, u64 x) {
#pragma unroll
    for (int j = 0; j < 8; ++j) {
        const u64 lo = x < best[j] ? x : best[j];
        const u64 hi = x < best[j] ? best[j] : x;
        best[j] = lo; x = hi;
    }
}

static __device__ __forceinline__ int cell_coord(float v) {
    int c = (int)floorf((v - GRID_LO) * (1.0f / CELL_S));
    c = c < 0 ? 0 : c;
    c = c > GRID_DIM - 1 ? GRID_DIM - 1 : c;
    return c;
}

// ---------------------------------------------------------------------------
// Dispatch 1 (after memset of cellCount/cellOff): cell histogram + cid (64
// blocks) fused with all f32->bf16 conversions (4096 blocks). Replaces r3's
// pack_conv; the packed |c|^2 array is gone (grid KNN uses true positions).
// ---------------------------------------------------------------------------
__global__ __launch_bounds__(256) void hist_conv(const float* __restrict__ pos,
                                                 u32* __restrict__ cellCount,
                                                 unsigned short* __restrict__ cid,
                                                 const float* __restrict__ x,
                                                 const float* __restrict__ Wq,
                                                 const float* __restrict__ Wkv,
                                                 const float* __restrict__ Wout,
                                                 short* __restrict__ xb,
                                                 short* __restrict__ wqkvt,
                                                 short* __restrict__ woutt)
{
    const int tid = threadIdx.x;
    if (blockIdx.x < 64) {
        const int i = blockIdx.x * 256 + tid;        // 0..16383
        const int b = i >> 13;
        const float px = pos[i * 3 + 0];
        const float py = pos[i * 3 + 1];
        const float pz = pos[i * 3 + 2];
        const int cx = cell_coord(px), cy = cell_coord(py), cz = cell_coord(pz);
        const int c = (cz * GRID_DIM + cy) * GRID_DIM + cx;
        cid[i] = (unsigned short)c;
        atomicAdd(&cellCount[b * NCELLS + c], 1u);
        return;
    }
    const int bid = blockIdx.x - 64;                 // 0..4095
    if (bid < 2048) {
        const int i = bid * 256 + tid;
        const float4 a = ((const float4*)x)[i * 2];
        const float4 b = ((const float4*)x)[i * 2 + 1];
        short8 w = {f2bf(a.x), f2bf(a.y), f2bf(a.z), f2bf(a.w),
                    f2bf(b.x), f2bf(b.y), f2bf(b.z), f2bf(b.w)};
        ((short8*)xb)[i] = w;
    } else if (bid < 2560) {
        const int o = (bid - 2048) * 256 + tid;      // n*256+k, n<512
        const int n = o >> 8, k = o & 255;
        wqkvt[o] = f2bf(Wq[(long)k * 512 + n]);
    } else if (bid < 3584) {
        const int o = (bid - 2560) * 256 + tid;      // n*256+k, n<1024
        const int n = o >> 8, k = o & 255;
        wqkvt[131072 + o] = f2bf(Wkv[(long)k * 1024 + n]);
    } else {
        const int o = (bid - 3584) * 256 + tid;      // n*512+k, n<256
        const int n = o >> 9, k = o & 511;
        woutt[o] = f2bf(Wout[(long)k * 256 + n]);
    }
}

// ---------------------------------------------------------------------------
// Dispatch 2: exclusive prefix sum of cellCount -> cellStart[b][0..32768].
// One block per batch; 256 threads x 128 bins; serial 256-way scan by tid 0.
// ---------------------------------------------------------------------------
__global__ __launch_bounds__(256) void scan_kernel(const u32* __restrict__ cellCount,
                                                   u32* __restrict__ cellStart)
{
    __shared__ u32 psum[256];
    const int b = blockIdx.x;
    const int tid = threadIdx.x;
    const u32* cnt = cellCount + b * NCELLS;
    u32* st = cellStart + b * (NCELLS + 1);

    u32 sum = 0;
    for (int j = 0; j < 128; ++j) sum += cnt[tid * 128 + j];
    psum[tid] = sum;
    __syncthreads();
    if (tid == 0) {
        u32 a = 0;
        for (int i = 0; i < 256; ++i) { const u32 t = psum[i]; psum[i] = a; a += t; }
    }
    __syncthreads();
    u32 run = psum[tid];
    for (int j = 0; j < 128; ++j) {
        st[tid * 128 + j] = run;
        run += cnt[tid * 128 + j];
    }
    if (tid == 255) st[NCELLS] = run;                // == 8192
}

// ---------------------------------------------------------------------------
// Dispatch 3: scatter points into cell-sorted order. Within-cell order is
// arbitrary (atomic) -- harmless, ties resolved by index in the u64 key.
// sortedPos.w carries the within-batch original index as int bits.
// ---------------------------------------------------------------------------
__global__ __launch_bounds__(256) void scatter_kernel(const float* __restrict__ pos,
                                                      const unsigned short* __restrict__ cid,
                                                      const u32* __restrict__ cellStart,
                                                      u32* __restrict__ cellOff,
                                                      float4* __restrict__ sortedPos)
{
    const int i = blockIdx.x * 256 + threadIdx.x;    // 0..16383
    const int b = i >> 13;
    const int li = i & 8191;
    const float px = pos[i * 3 + 0];
    const float py = pos[i * 3 + 1];
    const float pz = pos[i * 3 + 2];
    const int c = cid[i];
    const u32 dst = cellStart[b * (NCELLS + 1) + c] + atomicAdd(&cellOff[b * NCELLS + c], 1u);
    sortedPos[b * N_PTS + dst] = make_float4(px, py, pz, __int_as_float(li));
}

// ---------------------------------------------------------------------------
// Dispatch 4: q/kv GEMM (1536 blocks) + grid-KNN (first 64 blocks).
// KNN: one query per thread, queries processed in cell-sorted order (wave-
// mates are spatial neighbors -> coherent ring walks, L2-hot point lists).
// Expanding Chebyshev rings; cell lower-bound prune (boundary cells extend
// to +/-inf); terminate when ((r-1)*s)^2 > current 8th-best d2. Exact:
// true d2 always computed; u64 key (d2bits<<32)|idx matches reference
// tie-breaking. bd starts as NaN (from ~0 key) -- all NaN compares are
// false -> no prune/break until 8 real neighbors collected (safe).
// gemm: xb[16384,256] x wqkvt[1536,256]^T, 128x128 tile, BK=32, 4 waves
// 2x2, 16x16x32 MFMA; cols [0,512)->qall, [512,1536)->kvall.
// ---------------------------------------------------------------------------
__global__ __launch_bounds__(256) void gemm_knn(const short* __restrict__ A,
                                                const short* __restrict__ Bt,
                                                short* __restrict__ qall,
                                                short* __restrict__ kvall,
                                                const float4* __restrict__ sortedPos,
                                                const u32* __restrict__ cellStart,
                                                int* __restrict__ idxo)
{
    __shared__ short As[128][40];
    __shared__ short Bs[128][40];

    const int tid = threadIdx.x;

    if (blockIdx.x < 64) {
        // ================= grid-KNN block =================================
        const int i = blockIdx.x * 256 + tid;        // 0..16383 (sorted order)
        const int b = i >> 13;
        const int si = i & 8191;
        const float4* __restrict__ sp = sortedPos + b * N_PTS;
        const u32* __restrict__ cs = cellStart + b * (NCELLS + 1);

        const float4 q4 = sp[si];
        const float qx = q4.x, qy = q4.y, qz = q4.z;
        const int qi = __float_as_int(q4.w);         // my within-batch index
        const int qcx = cell_coord(qx), qcy = cell_coord(qy), qcz = cell_coord(qz);

        u64 best[8];
#pragma unroll
        for (int j = 0; j < 8; ++j) best[j] = ~0ULL;
        float bd = __uint_as_float(0xFFFFFFFFu);     // NaN -> no prune yet

        for (int r = 0; r < GRID_DIM; ++r) {
            if (r >= 2) {
                const float g = (float)(r - 1) * CELL_S;
                if (g * g > bd) break;               // NaN-safe (false -> keep going)
            }
            for (int dz = -r; dz <= r; ++dz) {
                const int z = qcz + dz;
                if (z < 0 || z > GRID_DIM - 1) continue;
                const int az_ = dz < 0 ? -dz : dz;
                for (int dy = -r; dy <= r; ++dy) {
                    const int y = qcy + dy;
                    if (y < 0 || y > GRID_DIM - 1) continue;
                    const int ay_ = dy < 0 ? -dy : dy;
                    const int xstep = (az_ == r || ay_ == r) ? 1 : 2 * r;
                    for (int dx = -r; dx <= r; dx += xstep) {
                        const int cx = qcx + dx;
                        if (cx < 0 || cx > GRID_DIM - 1) continue;
                        // cell lower-bound distance (boundary cells -> inf extent)
                        const float xlo = (cx == 0) ? -1.0e30f : GRID_LO + cx * CELL_S;
                        const float xhi = (cx == GRID_DIM - 1) ? 1.0e30f : GRID_LO + (cx + 1) * CELL_S;
                        const float ylo = (y == 0) ? -1.0e30f : GRID_LO + y * CELL_S;
                        const float yhi = (y == GRID_DIM - 1) ? 1.0e30f : GRID_LO + (y + 1) * CELL_S;
                        const float zlo = (z == 0) ? -1.0e30f : GRID_LO + z * CELL_S;
                        const float zhi = (z == GRID_DIM - 1) ? 1.0e30f : GRID_LO + (z + 1) * CELL_S;
                        const float ax = fmaxf(0.f, fmaxf(xlo - qx, qx - xhi));
                        const float ay = fmaxf(0.f, fmaxf(ylo - qy, qy - yhi));
                        const float az = fmaxf(0.f, fmaxf(zlo - qz, qz - zhi));
                        const float lbd2 = fmaf(ax, ax, fmaf(ay, ay, az * az));
                        if (lbd2 > bd) continue;     // NaN-safe
                        const int ci = (z * GRID_DIM + y) * GRID_DIM + cx;
                        const u32 s0 = cs[ci];
                        const u32 s1 = cs[ci + 1];
                        for (u32 u = s0; u < s1; ++u) {
                            const float4 c4 = sp[u];
                            const float ddx = c4.x - qx;
                            const float ddy = c4.y - qy;
                            const float ddz = c4.z - qz;
                            const float d2 = fmaf(ddx, ddx, fmaf(ddy, ddy, ddz * ddz));
                            const u64 key = ((u64)__float_as_uint(d2) << 32)
                                          | (u32)__float_as_int(c4.w);
                            if (key < best[7]) {
                                ins8(best, key);
                                bd = __uint_as_float((u32)(best[7] >> 32));
                            }
                        }
                    }
                }
            }
        }

        const long qglob = (long)b * N_PTS + qi;
#pragma unroll
        for (int j = 0; j < 8; ++j)
            idxo[qglob * 8 + j] = (int)(best[j] & 0xFFFFFFFFu);
        return;
    }

    // ================= GEMM block (1536 total) ============================
    const int id = blockIdx.x - 64;
    const int bx = id % 12;
    const int by = id / 12;

    const int lane = tid & 63;
    const int wv   = tid >> 6;
    const int quad = lane >> 4;
    const int l15  = lane & 15;
    const int m0 = by * 128;
    const int n0 = bx * 128;
    const int mh = (wv & 1) * 64, nh = (wv >> 1) * 64;

    const int srow  = tid >> 1;
    const int shalf = (tid & 1) * 16;
    const int Kd = 256;

    float4v acc[4][4];
#pragma unroll
    for (int i = 0; i < 4; ++i)
#pragma unroll
        for (int j = 0; j < 4; ++j) acc[i][j] = (float4v)(0.f);

    for (int k0 = 0; k0 < Kd; k0 += 32) {
        const short8* asrc = (const short8*)(A + (long)(m0 + srow) * Kd + k0 + shalf);
        const short8* bsrc = (const short8*)(Bt + (long)(n0 + srow) * Kd + k0 + shalf);
        *(short8*)&As[srow][shalf]     = asrc[0];
        *(short8*)&As[srow][shalf + 8] = asrc[1];
        *(short8*)&Bs[srow][shalf]     = bsrc[0];
        *(short8*)&Bs[srow][shalf + 8] = bsrc[1];
        __syncthreads();

        short8 af[4], bfv[4];
#pragma unroll
        for (int i = 0; i < 4; ++i)
            af[i] = *(const short8*)&As[mh + i * 16 + l15][quad * 8];
#pragma unroll
        for (int j = 0; j < 4; ++j)
            bfv[j] = *(const short8*)&Bs[nh + j * 16 + l15][quad * 8];
#pragma unroll
        for (int i = 0; i < 4; ++i)
#pragma unroll
            for (int j = 0; j < 4; ++j)
                acc[i][j] = __builtin_amdgcn_mfma_f32_16x16x32_bf16(af[i], bfv[j], acc[i][j], 0, 0, 0);
        __syncthreads();
    }

    short* Cb;
    int stride, cb;
    if (n0 < 512) { Cb = qall;  stride = 512;  cb = n0; }
    else          { Cb = kvall; stride = 1024; cb = n0 - 512; }

#pragma unroll
    for (int i = 0; i < 4; ++i)
#pragma unroll
        for (int j = 0; j < 4; ++j) {
            const int col = cb + nh + j * 16 + l15;
#pragma unroll
            for (int r = 0; r < 4; ++r) {
                const int row = m0 + mh + i * 16 + quad * 4 + r;
                Cb[(long)row * stride + col] = f2bf(acc[i][j][r]);
            }
        }
}

// ---------------------------------------------------------------------------
// Fused KNN attention, bf16 storage / f32 math (unchanged since round 5).
// ---------------------------------------------------------------------------
__global__ __launch_bounds__(256) void attn_kernel(const short* qall,
                                                   const short* __restrict__ kvall,
                                                   const int* __restrict__ idxp,
                                                   short* outp)
{
    __shared__ float attn_s[4][8][8];
    const int wave = threadIdx.x >> 6;
    const int lane = threadIdx.x & 63;
    const int g = blockIdx.x * 4 + wave;
    const int b = g >> 13;
    const int* myidx = idxp + (long)g * 8;

    {
        const int h = lane >> 3;
        const int k = lane & 7;
        const int j = myidx[k];
        const short8* qrow = (const short8*)(qall + (long)g * 512 + h * 64);
        const short8* krow = (const short8*)(kvall + ((long)(b * N_PTS + j)) * 1024 + h * 64);

        float dot = 0.f;
#pragma unroll
        for (int c = 0; c < 8; ++c) {
            const short8 qv = qrow[c];
            const short8 kv = krow[c];
#pragma unroll
            for (int e = 0; e < 8; ++e)
                dot = fmaf(bf2f(qv[e]), bf2f(kv[e]), dot);
        }
        dot *= 0.125f;

        float m = dot;
#pragma unroll
        for (int off = 1; off < 8; off <<= 1)
            m = fmaxf(m, __shfl_xor(m, off, 8));
        const float e = __expf(dot - m);
        float ssum = e;
#pragma unroll
        for (int off = 1; off < 8; off <<= 1)
            ssum += __shfl_xor(ssum, off, 8);
        attn_s[wave][h][k] = e / ssum;
    }
    __syncthreads();                      // drains q reads before aliased writes

    const int d8 = lane * 8;
    const int h2 = lane >> 3;
    float o[8] = {0.f, 0.f, 0.f, 0.f, 0.f, 0.f, 0.f, 0.f};
#pragma unroll
    for (int kk = 0; kk < 8; ++kk) {
        const int jj = myidx[kk];
        const float w = attn_s[wave][h2][kk];
        const short8 v = *(const short8*)(kvall + ((long)(b * N_PTS + jj)) * 1024 + 512 + d8);
#pragma unroll
        for (int e = 0; e < 8; ++e)
            o[e] = fmaf(w, bf2f(v[e]), o[e]);
    }
    short8 ov = {f2bf(o[0]), f2bf(o[1]), f2bf(o[2]), f2bf(o[3]),
                 f2bf(o[4]), f2bf(o[5]), f2bf(o[6]), f2bf(o[7])};
    *(short8*)(outp + (long)g * 512 + d8) = ov;
}

// ---------------------------------------------------------------------------
// Out-projection bf16 MFMA GEMM: C f32 = A[M,512] x Bt[256,512]^T + bias.
// ---------------------------------------------------------------------------
__global__ __launch_bounds__(256) void gemm_out(const short* __restrict__ A,
                                                const short* __restrict__ Bt,
                                                const float* __restrict__ bias,
                                                float* __restrict__ C,
                                                int N, int Kd)
{
    __shared__ short As[128][40];
    __shared__ short Bs[128][40];

    const int tid  = threadIdx.x;
    const int lane = tid & 63;
    const int wv   = tid >> 6;
    const int quad = lane >> 4;
    const int l15  = lane & 15;
    const int m0 = blockIdx.y * 128;
    const int n0 = blockIdx.x * 128;
    const int mh = (wv & 1) * 64, nh = (wv >> 1) * 64;

    const int srow  = tid >> 1;
    const int shalf = (tid & 1) * 16;

    float4v acc[4][4];
#pragma unroll
    for (int i = 0; i < 4; ++i)
#pragma unroll
        for (int j = 0; j < 4; ++j) acc[i][j] = (float4v)(0.f);

    for (int k0 = 0; k0 < Kd; k0 += 32) {
        const short8* asrc = (const short8*)(A + (long)(m0 + srow) * Kd + k0 + shalf);
        const short8* bsrc = (const short8*)(Bt + (long)(n0 + srow) * Kd + k0 + shalf);
        *(short8*)&As[srow][shalf]     = asrc[0];
        *(short8*)&As[srow][shalf + 8] = asrc[1];
        *(short8*)&Bs[srow][shalf]     = bsrc[0];
        *(short8*)&Bs[srow][shalf + 8] = bsrc[1];
        __syncthreads();

        short8 af[4], bfv[4];
#pragma unroll
        for (int i = 0; i < 4; ++i)
            af[i] = *(const short8*)&As[mh + i * 16 + l15][quad * 8];
#pragma unroll
        for (int j = 0; j < 4; ++j)
            bfv[j] = *(const short8*)&Bs[nh + j * 16 + l15][quad * 8];
#pragma unroll
        for (int i = 0; i < 4; ++i)
#pragma unroll
            for (int j = 0; j < 4; ++j)
                acc[i][j] = __builtin_amdgcn_mfma_f32_16x16x32_bf16(af[i], bfv[j], acc[i][j], 0, 0, 0);
        __syncthreads();
    }

#pragma unroll
    for (int i = 0; i < 4; ++i)
#pragma unroll
        for (int j = 0; j < 4; ++j) {
            const int col = n0 + nh + j * 16 + l15;
            const float bb = bias[col];
#pragma unroll
            for (int r = 0; r < 4; ++r) {
                const int row = m0 + mh + i * 16 + quad * 4 + r;
                C[(long)row * N + col] = acc[i][j][r] + bb;
            }
        }
}

// ---------------------------------------------------------------------------
extern "C" void kernel_launch(void* const* d_in, const int* in_sizes, int n_in,
                              void* d_out, int out_size, void* d_ws, size_t ws_size,
                              hipStream_t stream)
{
    const float* x    = (const float*)d_in[0];  // [2,8192,256]
    const float* pos  = (const float*)d_in[1];  // [2,8192,3]
    const float* Wq   = (const float*)d_in[2];  // [256,512]
    const float* Wkv  = (const float*)d_in[3];  // [256,1024]
    const float* Wout = (const float*)d_in[4];  // [512,256]
    const float* bout = (const float*)d_in[5];  // [256]
    float* out = (float*)d_out;                 // [2,8192,256] f32

    const int M = 16384;

    // workspace layout:
    char* ws = (char*)d_ws;
    int*   idxp  = (int*)ws;                          ws += 1 << 19;             // 512 KB
    short* qall  = (short*)ws;                        ws += (long)M * 512 * 2;   // 16 MB
    short* kvall = (short*)ws;                        ws += (long)M * 1024 * 2;  // 32 MB
    short* xb    = (short*)ws;                        ws += (long)M * 256 * 2;   // 8 MB
    short* wqkvt = (short*)ws;                        ws += 1536 * 256 * 2;      // 768 KB
    short* woutt = (short*)ws;                        ws += 256 * 512 * 2;       // 256 KB
    u32*  cellCount = (u32*)ws;                       ws += 2L * NCELLS * 4;     // 256 KB
    u32*  cellOff   = (u32*)ws;                       ws += 2L * NCELLS * 4;     // 256 KB (adjacent to cellCount)
    u32*  cellStart = (u32*)ws;                       ws += 2L * (NCELLS + 1) * 4 + 56; // ~256 KB
    unsigned short* cid = (unsigned short*)ws;        ws += (long)M * 2;         // 32 KB
    float4* sortedPos = (float4*)ws;                  ws += (long)M * 16;        // 256 KB

    // zero histogram + scatter counters (contiguous 512 KB)
    hipMemsetAsync(cellCount, 0, 4L * NCELLS * 4, stream);

    hist_conv<<<4160, 256, 0, stream>>>(pos, cellCount, cid, x, Wq, Wkv, Wout,
                                        xb, wqkvt, woutt);
    scan_kernel<<<2, 256, 0, stream>>>(cellCount, cellStart);
    scatter_kernel<<<64, 256, 0, stream>>>(pos, cid, cellStart, cellOff, sortedPos);
    gemm_knn<<<1600, 256, 0, stream>>>(xb, wqkvt, qall, kvall,
                                       sortedPos, cellStart, idxp);
    attn_kernel<<<M / 4, 256, 0, stream>>>(qall, kvall, idxp, qall);   // in-place
    gemm_out<<<dim3(2, 128), 256, 0, stream>>>(qall, woutt, bout, out, 256, 512);
}

// Round 5
// 282.076 us; speedup vs baseline: 3.4160x; 3.4160x over previous
//
#include <hip/hip_runtime.h>
#include <hip/hip_bf16.h>

#define N_PTS 8192
#define KNN 8

typedef __attribute__((ext_vector_type(8))) short short8;
typedef __attribute__((ext_vector_type(4))) float float4v;
typedef unsigned long long u64;

// f32 -> bf16 round-to-nearest-even (finite inputs only)
static __device__ __forceinline__ short f2bf(float f) {
    unsigned u = __float_as_uint(f);
    unsigned r = (u + 0x7FFFu + ((u >> 16) & 1u)) >> 16;
    return (short)r;
}
static __device__ __forceinline__ float bf2f(short s) {
    return __uint_as_float(((unsigned)(unsigned short)s) << 16);
}

// monotone float -> u32 key (handles negative d' = |c|^2 - 2 q.c)
static __device__ __forceinline__ unsigned sortkey(float f) {
    unsigned u = __float_as_uint(f);
    return u ^ (((unsigned)((int)u >> 31)) | 0x80000000u);
}

static __device__ __forceinline__ void ins8(u64* best, u64 x) {
#pragma unroll
    for (int j = 0; j < 8; ++j) {
        const u64 lo = x < best[j] ? x : best[j];
        const u64 hi = x < best[j] ? best[j] : x;
        best[j] = lo; x = hi;
    }
}

// VGPR-pinned min update: prevents the compiler from parking the persistent
// accumulator in an AGPR (r0-r3 diagnosis: VGPR_Count 40-52 with 64 floats
// of live bucket state + ~4x VALU inflation + zero memory traffic ==
// v_accvgpr_read/write churn around every fmin). The "v" constraint makes
// AGPR placement impossible at each use.
static __device__ __forceinline__ void vmin_acc(float& acc, float d) {
    asm("v_min_f32 %0, %0, %1" : "+v"(acc) : "v"(d));
}
// VGPR-pinned compare-exchange for the insertion networks.
static __device__ __forceinline__ void vsort2(float& a, float& x) {
    float lo, hi;
    asm("v_min_f32 %0, %2, %3\n\tv_max_f32 %1, %2, %3"
        : "=&v"(lo), "=v"(hi) : "v"(a), "v"(x));
    a = lo; x = hi;
}

// ---------------------------------------------------------------------------
// Dispatch 1: knn_partial (1024 blocks) + all f32->bf16 conversions (4096
// blocks), 1:4 interleave (r1 structure, best verified at 303.4 us total).
//
// knn: one query per thread, 16 partitions x 512 cand. Candidates staged in
// LDS as AoS float4 (x, y, z, |c|^2); distance surrogate d' = |c|^2 - 2 q.c
// (monotone in true d2). Pass 1: 32 rotating bucket minima, ASM-PINNED to
// VGPRs (the round-5 fix). Threshold t = 8th smallest bucket min (>= 8
// survivors guaranteed). Pass 2: exec-masked collect of u16 local indices
// (cap 16 + overflow slot). Exact top-8 over survivors via u64 keys;
// exact full-rescan fallback if cnt > 16 (statistically never).
// ---------------------------------------------------------------------------
__global__ __launch_bounds__(256) void fused_knn_conv(const float* __restrict__ pos,
                                                      u64* __restrict__ partial,
                                                      const float* __restrict__ x,
                                                      const float* __restrict__ Wq,
                                                      const float* __restrict__ Wkv,
                                                      const float* __restrict__ Wout,
                                                      short* __restrict__ xb,
                                                      short* __restrict__ wqkvt,
                                                      short* __restrict__ woutt)
{
    __shared__ __align__(16) char smem[16896];
    const int tid = threadIdx.x;
    const int g5 = blockIdx.x / 5;
    const int r5 = blockIdx.x % 5;

    if (r5 == 0) {
        // ================= KNN block (1024 total) =========================
        const int kb = g5;                       // 0..1023
        float4* cand = (float4*)smem;            // 512 x (x,y,z,|c|^2) = 8192 B
        unsigned short* buf = (unsigned short*)(smem + 8192);  // [256][17] u16

        const int p   = kb & 15;
        const int qg  = kb >> 4;
        const int batch = qg >> 5;
        const int q_in_b = (qg & 31) * 256 + tid;
        const float* bpos = pos + (long)batch * N_PTS * 3;

        if (tid < 128) {
            const float* src = bpos + (p * 512 + tid * 4) * 3;
            const float4 f0 = *(const float4*)(src);
            const float4 f1 = *(const float4*)(src + 4);
            const float4 f2 = *(const float4*)(src + 8);
            const int c0 = tid * 4;
            cand[c0 + 0] = make_float4(f0.x, f0.y, f0.z,
                                       fmaf(f0.x, f0.x, fmaf(f0.y, f0.y, f0.z * f0.z)));
            cand[c0 + 1] = make_float4(f0.w, f1.x, f1.y,
                                       fmaf(f0.w, f0.w, fmaf(f1.x, f1.x, f1.y * f1.y)));
            cand[c0 + 2] = make_float4(f1.z, f1.w, f2.x,
                                       fmaf(f1.z, f1.z, fmaf(f1.w, f1.w, f2.x * f2.x)));
            cand[c0 + 3] = make_float4(f2.y, f2.z, f2.w,
                                       fmaf(f2.y, f2.y, fmaf(f2.z, f2.z, f2.w * f2.w)));
        }
        __syncthreads();

        const float qx = bpos[q_in_b * 3 + 0];
        const float qy = bpos[q_in_b * 3 + 1];
        const float qz = bpos[q_in_b * 3 + 2];
        const float nqx = -2.0f * qx;
        const float nqy = -2.0f * qy;
        const float nqz = -2.0f * qz;

        float bmin[32];
#pragma unroll
        for (int j = 0; j < 32; ++j) bmin[j] = 3.0e38f;

        for (int base = 0; base < 512; base += 32) {
#pragma unroll
            for (int g = 0; g < 32; ++g) {
                const float4 c = cand[base + g];
                const float d = fmaf(c.x, nqx, fmaf(c.y, nqy, fmaf(c.z, nqz, c.w)));
                vmin_acc(bmin[g], d);                // VGPR-pinned
            }
        }

        float t8[8];
#pragma unroll
        for (int j = 0; j < 8; ++j) t8[j] = 3.0e38f;
#pragma unroll
        for (int i = 0; i < 32; ++i) {
            float x_ = bmin[i];
#pragma unroll
            for (int j = 0; j < 8; ++j)
                vsort2(t8[j], x_);                   // VGPR-pinned
        }
        const float t = t8[7];

        int cnt = 0;
        for (int base = 0; base < 512; base += 32) {
#pragma unroll
            for (int g = 0; g < 32; ++g) {
                const float4 c = cand[base + g];
                const float d = fmaf(c.x, nqx, fmaf(c.y, nqy, fmaf(c.z, nqz, c.w)));
                if (d <= t) {
                    buf[tid * 17 + (cnt < 16 ? cnt : 16)] = (unsigned short)(base + g);
                    ++cnt;
                }
            }
        }

        u64 best[8];
#pragma unroll
        for (int j = 0; j < 8; ++j) best[j] = ~0ULL;

        if (cnt <= 16) {
            for (int u = 0; u < cnt; ++u) {
                const int i = buf[tid * 17 + u];
                const float4 c = cand[i];
                const float d = fmaf(c.x, nqx, fmaf(c.y, nqy, fmaf(c.z, nqz, c.w)));
                ins8(best, ((u64)sortkey(d) << 32) | (unsigned)(p * 512 + i));
            }
        } else {
            for (int i = 0; i < 512; ++i) {     // statistically-never fallback
                const float4 c = cand[i];
                const float d = fmaf(c.x, nqx, fmaf(c.y, nqy, fmaf(c.z, nqz, c.w)));
                const u64 x_ = ((u64)sortkey(d) << 32) | (unsigned)(p * 512 + i);
                if (x_ < best[7]) ins8(best, x_);
            }
        }

        const long qglob = (long)batch * N_PTS + q_in_b;
#pragma unroll
        for (int j = 0; j < 8; ++j)
            partial[(long)(p * 8 + j) * 16384 + qglob] = best[j];   // coalesced

    } else {
        // ================= conv block (4096 total, LDS-light) =============
        const int bid = g5 * 4 + (r5 - 1);      // 0..4095
        if (bid < 2048) {
            const int i = bid * 256 + tid;
            const float4 a = ((const float4*)x)[i * 2];
            const float4 b = ((const float4*)x)[i * 2 + 1];
            short8 w = {f2bf(a.x), f2bf(a.y), f2bf(a.z), f2bf(a.w),
                        f2bf(b.x), f2bf(b.y), f2bf(b.z), f2bf(b.w)};
            ((short8*)xb)[i] = w;
        } else if (bid < 2560) {
            const int o = (bid - 2048) * 256 + tid;      // n*256+k, n<512
            const int n = o >> 8, k = o & 255;
            wqkvt[o] = f2bf(Wq[(long)k * 512 + n]);
        } else if (bid < 3584) {
            const int o = (bid - 2560) * 256 + tid;      // n*256+k, n<1024
            const int n = o >> 8, k = o & 255;
            wqkvt[131072 + o] = f2bf(Wkv[(long)k * 1024 + n]);
        } else {
            const int o = (bid - 3584) * 256 + tid;      // n*512+k, n<256
            const int n = o >> 9, k = o & 511;
            woutt[o] = f2bf(Wout[(long)k * 256 + n]);
        }
    }
}

// ---------------------------------------------------------------------------
// Dispatch 2: q/kv GEMM (1536 blocks) + knn_merge (first 64 blocks).
// merge uses zero LDS; co-resident with the gemm flood it hides completely.
// gemm: xb[16384,256] x wqkvt[1536,256]^T, 128x128 tile, BK=32, 4 waves 2x2,
// 16x16x32 MFMA; cols [0,512) -> qall (stride 512), [512,1536) -> kvall.
// ---------------------------------------------------------------------------
__global__ __launch_bounds__(256) void fused_gemm_merge(const short* __restrict__ A,
                                                        const short* __restrict__ Bt,
                                                        short* __restrict__ qall,
                                                        short* __restrict__ kvall,
                                                        const u64* __restrict__ partial,
                                                        int* __restrict__ idxo)
{
    __shared__ short As[128][40];
    __shared__ short Bs[128][40];

    const int tid = threadIdx.x;

    if (blockIdx.x < 64) {
        // ================= merge block (zero LDS) =========================
        const int q = blockIdx.x * 256 + tid;
        u64 best[8];
#pragma unroll
        for (int j = 0; j < 8; ++j) best[j] = ~0ULL;
        for (int s = 0; s < 128; ++s) {
            u64 x = partial[(long)s * 16384 + q];
            if (x < best[7]) ins8(best, x);
        }
#pragma unroll
        for (int j = 0; j < 8; ++j)
            idxo[(long)q * 8 + j] = (int)(best[j] & 0xFFFFFFFFu);
        return;
    }

    // ================= GEMM block (1536 total) ============================
    const int id = blockIdx.x - 64;
    const int bx = id % 12;
    const int by = id / 12;

    const int lane = tid & 63;
    const int wv   = tid >> 6;
    const int quad = lane >> 4;
    const int l15  = lane & 15;
    const int m0 = by * 128;
    const int n0 = bx * 128;
    const int mh = (wv & 1) * 64, nh = (wv >> 1) * 64;

    const int srow  = tid >> 1;
    const int shalf = (tid & 1) * 16;
    const int Kd = 256;

    float4v acc[4][4];
#pragma unroll
    for (int i = 0; i < 4; ++i)
#pragma unroll
        for (int j = 0; j < 4; ++j) acc[i][j] = (float4v)(0.f);

    for (int k0 = 0; k0 < Kd; k0 += 32) {
        const short8* asrc = (const short8*)(A + (long)(m0 + srow) * Kd + k0 + shalf);
        const short8* bsrc = (const short8*)(Bt + (long)(n0 + srow) * Kd + k0 + shalf);
        *(short8*)&As[srow][shalf]     = asrc[0];
        *(short8*)&As[srow][shalf + 8] = asrc[1];
        *(short8*)&Bs[srow][shalf]     = bsrc[0];
        *(short8*)&Bs[srow][shalf + 8] = bsrc[1];
        __syncthreads();

        short8 af[4], bfv[4];
#pragma unroll
        for (int i = 0; i < 4; ++i)
            af[i] = *(const short8*)&As[mh + i * 16 + l15][quad * 8];
#pragma unroll
        for (int j = 0; j < 4; ++j)
            bfv[j] = *(const short8*)&Bs[nh + j * 16 + l15][quad * 8];
#pragma unroll
        for (int i = 0; i < 4; ++i)
#pragma unroll
            for (int j = 0; j < 4; ++j)
                acc[i][j] = __builtin_amdgcn_mfma_f32_16x16x32_bf16(af[i], bfv[j], acc[i][j], 0, 0, 0);
        __syncthreads();
    }

    short* Cb;
    int stride, cb;
    if (n0 < 512) { Cb = qall;  stride = 512;  cb = n0; }
    else          { Cb = kvall; stride = 1024; cb = n0 - 512; }

#pragma unroll
    for (int i = 0; i < 4; ++i)
#pragma unroll
        for (int j = 0; j < 4; ++j) {
            const int col = cb + nh + j * 16 + l15;
#pragma unroll
            for (int r = 0; r < 4; ++r) {
                const int row = m0 + mh + i * 16 + quad * 4 + r;
                Cb[(long)row * stride + col] = f2bf(acc[i][j][r]);
            }
        }
}

// ---------------------------------------------------------------------------
// Fused KNN attention, bf16 storage / f32 math (unchanged since round 5).
// ---------------------------------------------------------------------------
__global__ __launch_bounds__(256) void attn_kernel(const short* qall,
                                                   const short* __restrict__ kvall,
                                                   const int* __restrict__ idxp,
                                                   short* outp)
{
    __shared__ float attn_s[4][8][8];
    const int wave = threadIdx.x >> 6;
    const int lane = threadIdx.x & 63;
    const int g = blockIdx.x * 4 + wave;
    const int b = g >> 13;
    const int* myidx = idxp + (long)g * 8;

    {
        const int h = lane >> 3;
        const int k = lane & 7;
        const int j = myidx[k];
        const short8* qrow = (const short8*)(qall + (long)g * 512 + h * 64);
        const short8* krow = (const short8*)(kvall + ((long)(b * N_PTS + j)) * 1024 + h * 64);

        float dot = 0.f;
#pragma unroll
        for (int c = 0; c < 8; ++c) {
            const short8 qv = qrow[c];
            const short8 kv = krow[c];
#pragma unroll
            for (int e = 0; e < 8; ++e)
                dot = fmaf(bf2f(qv[e]), bf2f(kv[e]), dot);
        }
        dot *= 0.125f;

        float m = dot;
#pragma unroll
        for (int off = 1; off < 8; off <<= 1)
            m = fmaxf(m, __shfl_xor(m, off, 8));
        const float e = __expf(dot - m);
        float ssum = e;
#pragma unroll
        for (int off = 1; off < 8; off <<= 1)
            ssum += __shfl_xor(ssum, off, 8);
        attn_s[wave][h][k] = e / ssum;
    }
    __syncthreads();                      // drains q reads before aliased writes

    const int d8 = lane * 8;
    const int h2 = lane >> 3;
    float o[8] = {0.f, 0.f, 0.f, 0.f, 0.f, 0.f, 0.f, 0.f};
#pragma unroll
    for (int kk = 0; kk < 8; ++kk) {
        const int jj = myidx[kk];
        const float w = attn_s[wave][h2][kk];
        const short8 v = *(const short8*)(kvall + ((long)(b * N_PTS + jj)) * 1024 + 512 + d8);
#pragma unroll
        for (int e = 0; e < 8; ++e)
            o[e] = fmaf(w, bf2f(v[e]), o[e]);
    }
    short8 ov = {f2bf(o[0]), f2bf(o[1]), f2bf(o[2]), f2bf(o[3]),
                 f2bf(o[4]), f2bf(o[5]), f2bf(o[6]), f2bf(o[7])};
    *(short8*)(outp + (long)g * 512 + d8) = ov;
}

// ---------------------------------------------------------------------------
// Out-projection bf16 MFMA GEMM: C f32 = A[M,512] x Bt[256,512]^T + bias.
// ---------------------------------------------------------------------------
__global__ __launch_bounds__(256) void gemm_out(const short* __restrict__ A,
                                                const short* __restrict__ Bt,
                                                const float* __restrict__ bias,
                                                float* __restrict__ C,
                                                int N, int Kd)
{
    __shared__ short As[128][40];
    __shared__ short Bs[128][40];

    const int tid  = threadIdx.x;
    const int lane = tid & 63;
    const int wv   = tid >> 6;
    const int quad = lane >> 4;
    const int l15  = lane & 15;
    const int m0 = blockIdx.y * 128;
    const int n0 = blockIdx.x * 128;
    const int mh = (wv & 1) * 64, nh = (wv >> 1) * 64;

    const int srow  = tid >> 1;
    const int shalf = (tid & 1) * 16;

    float4v acc[4][4];
#pragma unroll
    for (int i = 0; i < 4; ++i)
#pragma unroll
        for (int j = 0; j < 4; ++j) acc[i][j] = (float4v)(0.f);

    for (int k0 = 0; k0 < Kd; k0 += 32) {
        const short8* asrc = (const short8*)(A + (long)(m0 + srow) * Kd + k0 + shalf);
        const short8* bsrc = (const short8*)(Bt + (long)(n0 + srow) * Kd + k0 + shalf);
        *(short8*)&As[srow][shalf]     = asrc[0];
        *(short8*)&As[srow][shalf + 8] = asrc[1];
        *(short8*)&Bs[srow][shalf]     = bsrc[0];
        *(short8*)&Bs[srow][shalf + 8] = bsrc[1];
        __syncthreads();

        short8 af[4], bfv[4];
#pragma unroll
        for (int i = 0; i < 4; ++i)
            af[i] = *(const short8*)&As[mh + i * 16 + l15][quad * 8];
#pragma unroll
        for (int j = 0; j < 4; ++j)
            bfv[j] = *(const short8*)&Bs[nh + j * 16 + l15][quad * 8];
#pragma unroll
        for (int i = 0; i < 4; ++i)
#pragma unroll
            for (int j = 0; j < 4; ++j)
                acc[i][j] = __builtin_amdgcn_mfma_f32_16x16x32_bf16(af[i], bfv[j], acc[i][j], 0, 0, 0);
        __syncthreads();
    }

#pragma unroll
    for (int i = 0; i < 4; ++i)
#pragma unroll
        for (int j = 0; j < 4; ++j) {
            const int col = n0 + nh + j * 16 + l15;
            const float bb = bias[col];
#pragma unroll
            for (int r = 0; r < 4; ++r) {
                const int row = m0 + mh + i * 16 + quad * 4 + r;
                C[(long)row * N + col] = acc[i][j][r] + bb;
            }
        }
}

// ---------------------------------------------------------------------------
extern "C" void kernel_launch(void* const* d_in, const int* in_sizes, int n_in,
                              void* d_out, int out_size, void* d_ws, size_t ws_size,
                              hipStream_t stream)
{
    const float* x    = (const float*)d_in[0];  // [2,8192,256]
    const float* pos  = (const float*)d_in[1];  // [2,8192,3]
    const float* Wq   = (const float*)d_in[2];  // [256,512]
    const float* Wkv  = (const float*)d_in[3];  // [256,1024]
    const float* Wout = (const float*)d_in[4];  // [512,256]
    const float* bout = (const float*)d_in[5];  // [256]
    float* out = (float*)d_out;                 // [2,8192,256] f32

    const int M = 16384;

    // workspace layout:
    char* ws = (char*)d_ws;
    int*   idxp  = (int*)ws;                          ws += 1 << 19;             // 512 KB
    short* qall  = (short*)ws;                        ws += (long)M * 512 * 2;   // 16 MB
    short* kvall = (short*)ws;                        ws += (long)M * 1024 * 2;  // 32 MB
    short* xb    = (short*)ws;                        ws += (long)M * 256 * 2;   // 8 MB
    short* wqkvt = (short*)ws;                        ws += 1536 * 256 * 2;      // 768 KB
    short* woutt = (short*)ws;                        ws += 256 * 512 * 2;       // 256 KB
    u64*  partial = (u64*)ws;                         ws += (long)128 * 16384 * 8; // 16 MB

    fused_knn_conv<<<5120, 256, 0, stream>>>(pos, partial, x, Wq, Wkv, Wout,
                                             xb, wqkvt, woutt);
    fused_gemm_merge<<<1600, 256, 0, stream>>>(xb, wqkvt, qall, kvall, partial, idxp);
    attn_kernel<<<M / 4, 256, 0, stream>>>(qall, kvall, idxp, qall);   // in-place
    gemm_out<<<dim3(2, 128), 256, 0, stream>>>(qall, woutt, bout, out, 256, 512);
}